// Round 1
// baseline (3371.196 us; speedup 1.0000x reference)
//
#include <hip/hip_runtime.h>

#define T_ 256
#define B_ 32
#define NL 4
#define H_ 256
#define V_ 32000
#define M_ 8192   // T_*B_

typedef float  f32x4  __attribute__((ext_vector_type(4)));
typedef short  s16x8  __attribute__((ext_vector_type(8)));
typedef __bf16 bf16x8 __attribute__((ext_vector_type(8)));

__device__ __forceinline__ unsigned short f2bf(float f) {
    unsigned u = __float_as_uint(f);
    u = (u + 0x7fffu + ((u >> 16) & 1u)) >> 16;
    return (unsigned short)u;
}

__device__ __forceinline__ f32x4 mfma16(s16x8 a, s16x8 b, f32x4 c) {
    union { s16x8 s; bf16x8 b; } ua, ub;
    ua.s = a; ub.s = b;
    return __builtin_amdgcn_mfma_f32_16x16x32_bf16(ua.b, ub.b, c, 0, 0, 0);
}

__device__ __forceinline__ float tanh_fast(float x) {
    float e = __expf(2.0f * x);
    return 1.0f - 2.0f / (e + 1.0f);   // large |x| -> +-1 via inf/0, safe
}

// convert 8 consecutive f32 -> bf16 fragment
__device__ __forceinline__ s16x8 load_w8(const float* p) {
    float4 w0 = *(const float4*)p;
    float4 w1 = *(const float4*)(p + 4);
    s16x8 f;
    f[0] = (short)f2bf(w0.x); f[1] = (short)f2bf(w0.y);
    f[2] = (short)f2bf(w0.z); f[3] = (short)f2bf(w0.w);
    f[4] = (short)f2bf(w1.x); f[5] = (short)f2bf(w1.y);
    f[6] = (short)f2bf(w1.z); f[7] = (short)f2bf(w1.w);
    return f;
}

// ---------------- embedding gather: x0[row][j] = bf16(emb[tok[row]][j]) -----
__global__ __launch_bounds__(256) void k_embed(const int* __restrict__ tok,
                                               const float* __restrict__ emb,
                                               unsigned short* __restrict__ xout) {
    int row = blockIdx.x;
    int j   = threadIdx.x;
    int t   = tok[row];
    xout[row * H_ + j] = f2bf(emb[(size_t)t * H_ + j]);
}

// ---------------- f32 -> bf16 bulk convert (dec_W) --------------------------
__global__ __launch_bounds__(256) void k_cvt(const float* __restrict__ src,
                                             unsigned short* __restrict__ dst,
                                             int n4) {
    int i = blockIdx.x * blockDim.x + threadIdx.x;
    if (i >= n4) return;
    float4 v = *(const float4*)(src + (size_t)i * 4);
    short4 o;
    o.x = (short)f2bf(v.x); o.y = (short)f2bf(v.y);
    o.z = (short)f2bf(v.z); o.w = (short)f2bf(v.w);
    *(short4*)(dst + (size_t)i * 4) = o;
}

// ---------------- input GEMM: X[m][n] = sum_k xin[m][k]*W[n][k]  (f32 out) --
// grid (4, 128): bx = 64-col block, by = 64-row block; 4 waves, wave w owns 16 cols
__global__ __launch_bounds__(256) void k_gemm_in(const unsigned short* __restrict__ xin,
                                                 const float* __restrict__ W,
                                                 float* __restrict__ X) {
    int tid = threadIdx.x;
    int wv = tid >> 6, ln = tid & 63;
    int q = ln >> 4, c = ln & 15;
    int n0 = blockIdx.x * 64 + wv * 16;
    int m0 = blockIdx.y * 64;
    int n  = n0 + c;

    s16x8 bfrag[8];
#pragma unroll
    for (int kk = 0; kk < 8; ++kk)
        bfrag[kk] = load_w8(W + n * H_ + kk * 32 + q * 8);

#pragma unroll
    for (int mt = 0; mt < 4; ++mt) {
        int mbase = m0 + mt * 16;
        f32x4 acc = {0.f, 0.f, 0.f, 0.f};
#pragma unroll
        for (int kk = 0; kk < 8; ++kk) {
            s16x8 a = *(const s16x8*)(xin + (size_t)(mbase + c) * H_ + kk * 32 + q * 8);
            acc = mfma16(a, bfrag[kk], acc);
        }
#pragma unroll
        for (int r = 0; r < 4; ++r)
            X[(size_t)(mbase + q * 4 + r) * H_ + n] = acc[r];
    }
}

// ---------------- sequential recurrence over T steps (one layer) ------------
// 1 block, 1024 threads = 16 waves; wave w owns output cols [16w,16w+16)
// h kept in LDS (double buffered) in MFMA-A fragment-packed layout:
//   element (m,k) at short index ((k>>3)*32 + m)*8 + (k&7)
__global__ __launch_bounds__(1024) void k_recur(const float* __restrict__ X,
                                                const float* __restrict__ Whh,
                                                const float* __restrict__ bih,
                                                const float* __restrict__ bhh,
                                                unsigned short* __restrict__ xout,
                                                float* __restrict__ hout) {
    __shared__ short hbuf[2][B_ * H_];   // 2 x 16 KB

    int tid = threadIdx.x;
    int wv = tid >> 6, ln = tid & 63;
    int q = ln >> 4, c = ln & 15;
    int n = wv * 16 + c;

    float bs = bih[n] + bhh[n];

    s16x8 bfrag[8];   // persistent W_hh fragments: W[n][kk*32+q*8 .. +7]
#pragma unroll
    for (int kk = 0; kk < 8; ++kk)
        bfrag[kk] = load_w8(Whh + n * H_ + kk * 32 + q * 8);

#pragma unroll
    for (int i = 0; i < 8; ++i) hbuf[1][tid * 8 + i] = 0;   // h(-1) = 0
    __syncthreads();

    for (int t = 0; t < T_; ++t) {
        const short* rd = hbuf[1 - (t & 1)];
        short*       wr = hbuf[t & 1];

        f32x4 acc0, acc1;   // M-tiles 0 (rows 0-15) and 1 (rows 16-31)
#pragma unroll
        for (int r = 0; r < 4; ++r) {
            acc0[r] = X[(size_t)(t * B_ + q * 4 + r) * H_ + n];
            acc1[r] = X[(size_t)(t * B_ + 16 + q * 4 + r) * H_ + n];
        }
#pragma unroll
        for (int kk = 0; kk < 8; ++kk) {
            s16x8 a0 = *(const s16x8*)(rd + ((kk * 4 + q) * 32 + c) * 8);
            s16x8 a1 = *(const s16x8*)(rd + ((kk * 4 + q) * 32 + 16 + c) * 8);
            acc0 = mfma16(a0, bfrag[kk], acc0);
            acc1 = mfma16(a1, bfrag[kk], acc1);
        }
#pragma unroll
        for (int mt = 0; mt < 2; ++mt) {
#pragma unroll
            for (int r = 0; r < 4; ++r) {
                int m = mt * 16 + q * 4 + r;
                float v = (mt ? acc1[r] : acc0[r]) + bs;
                v = tanh_fast(v);
                unsigned short vb = f2bf(v);
                wr[((n >> 3) * 32 + m) * 8 + (n & 7)] = (short)vb;   // next step's A-frag
                xout[(size_t)(t * B_ + m) * H_ + n] = vb;            // layer output
                if (t == T_ - 1) hout[m * H_ + n] = v;               // final hidden
            }
        }
        __syncthreads();
    }
}

// ---------------- decode GEMM: out[m][v] = sum_k A[m][k]*Bm[v][k] + bias[v] -
// 128x128 block tile, K=256 single pass; 4 waves in 2x2, each 64x64
#define LDP 264   // padded row length in shorts (528 B -> conflict-free b128)
__global__ __launch_bounds__(256) void k_decode(const unsigned short* __restrict__ A,
                                                const unsigned short* __restrict__ Bm,
                                                const float* __restrict__ bias,
                                                float* __restrict__ out) {
    extern __shared__ __align__(16) short sm[];
    short* lA = sm;              // 128 x LDP
    short* lB = sm + 128 * LDP;  // 128 x LDP

    int tid = threadIdx.x;
    int n0g = blockIdx.x * 128;
    int m0g = blockIdx.y * 128;

#pragma unroll
    for (int it = 0; it < 16; ++it) {
        int u = it * 256 + tid;
        int mr = u >> 5;       // 0..127
        int ko = u & 31;       // 16B chunk within row
        *(s16x8*)(lA + mr * LDP + ko * 8) =
            *(const s16x8*)(A + (size_t)(m0g + mr) * H_ + ko * 8);
        *(s16x8*)(lB + mr * LDP + ko * 8) =
            *(const s16x8*)(Bm + (size_t)(n0g + mr) * H_ + ko * 8);
    }
    __syncthreads();

    int wv = tid >> 6, ln = tid & 63;
    int q = ln >> 4, c = ln & 15;
    int wm = (wv >> 1) * 64, wn = (wv & 1) * 64;

    f32x4 acc[4][4];
#pragma unroll
    for (int i = 0; i < 4; ++i)
#pragma unroll
        for (int j = 0; j < 4; ++j) acc[i][j] = (f32x4){0.f, 0.f, 0.f, 0.f};

#pragma unroll
    for (int kk = 0; kk < 8; ++kk) {
        s16x8 a[4], b[4];
#pragma unroll
        for (int mt = 0; mt < 4; ++mt)
            a[mt] = *(const s16x8*)(lA + (wm + mt * 16 + c) * LDP + kk * 32 + q * 8);
#pragma unroll
        for (int nt = 0; nt < 4; ++nt)
            b[nt] = *(const s16x8*)(lB + (wn + nt * 16 + c) * LDP + kk * 32 + q * 8);
#pragma unroll
        for (int mt = 0; mt < 4; ++mt)
#pragma unroll
            for (int nt = 0; nt < 4; ++nt)
                acc[mt][nt] = mfma16(a[mt], b[nt], acc[mt][nt]);
    }

#pragma unroll
    for (int nt = 0; nt < 4; ++nt) {
        int col = n0g + wn + nt * 16 + c;
        float bv = bias[col];
#pragma unroll
        for (int mt = 0; mt < 4; ++mt) {
            int row = m0g + wm + mt * 16 + q * 4;
#pragma unroll
            for (int r = 0; r < 4; ++r)
                out[(size_t)(row + r) * V_ + col] = acc[mt][nt][r] + bv;
        }
    }
}

// ---------------------------------------------------------------------------
extern "C" void kernel_launch(void* const* d_in, const int* in_sizes, int n_in,
                              void* d_out, int out_size, void* d_ws, size_t ws_size,
                              hipStream_t stream) {
    const int*   tokens = (const int*)d_in[0];
    const float* emb    = (const float*)d_in[1];
    const float* W_ih   = (const float*)d_in[2];
    const float* W_hh   = (const float*)d_in[3];
    const float* b_ih   = (const float*)d_in[4];
    const float* b_hh   = (const float*)d_in[5];
    const float* dec_W  = (const float*)d_in[6];
    const float* dec_b  = (const float*)d_in[7];

    float* out = (float*)d_out;
    float* hid = out + (size_t)M_ * V_;   // hidden [L,B,H] after decoded [T,B,V]

    char* ws = (char*)d_ws;
    unsigned short* x_a    = (unsigned short*)(ws);                  // 4 MB
    unsigned short* x_b    = (unsigned short*)(ws + (4u << 20));     // 4 MB
    float*          Xbuf   = (float*)(ws + (8u << 20));              // 8 MB
    unsigned short* decW16 = (unsigned short*)(ws + (16u << 20));    // 16 MB

    (void)in_sizes; (void)n_in; (void)out_size; (void)ws_size;

    hipFuncSetAttribute((const void*)k_decode,
                        hipFuncAttributeMaxDynamicSharedMemorySize,
                        2 * 128 * LDP * (int)sizeof(short));

    k_embed<<<M_, 256, 0, stream>>>(tokens, emb, x_a);
    k_cvt<<<(V_ * H_ / 4 + 255) / 256, 256, 0, stream>>>(dec_W, decW16, V_ * H_ / 4);

    const unsigned short* xin = x_a;
    unsigned short* xout = x_b;
    for (int l = 0; l < NL; ++l) {
        k_gemm_in<<<dim3(4, 128), 256, 0, stream>>>(xin, W_ih + l * H_ * H_, Xbuf);
        k_recur<<<1, 1024, 0, stream>>>(Xbuf, W_hh + l * H_ * H_,
                                        b_ih + l * H_, b_hh + l * H_,
                                        xout, hid + l * B_ * H_);
        const unsigned short* t = xout; xout = (unsigned short*)xin; xin = t;
    }
    // after 4 ping-pongs the top-layer outputs are back in x_a (== xin)
    k_decode<<<dim3(V_ / 128, M_ / 128), 256, 2 * 128 * LDP * sizeof(short), stream>>>(
        xin, decW16, dec_b, out);
}